// Round 1
// baseline (74.113 us; speedup 1.0000x reference)
//
#include <hip/hip_runtime.h>
#include <math.h>

#define Bn 16
#define Ln 1444      // 38*38
#define An 4
#define NCn 21
#define Cn 64
#define NBn 23       // ceil(1444/64)

// ---------------- K1: per-position class via softmax argmax ----------------
__global__ __launch_bounds__(256) void k_classify(const float* __restrict__ cls_pred,
                                                  int* __restrict__ cls_idx) {
    int t = blockIdx.x * 256 + threadIdx.x;
    if (t >= Bn * Ln) return;
    const float* p = cls_pred + (size_t)t * 84;
    float x[84];
#pragma unroll
    for (int i = 0; i < 21; i++) {
        float4 v = reinterpret_cast<const float4*>(p)[i];
        x[4 * i] = v.x; x[4 * i + 1] = v.y; x[4 * i + 2] = v.z; x[4 * i + 3] = v.w;
    }
    float best = -1.f;
    int bi = 0;
#pragma unroll
    for (int a = 0; a < 4; a++) {
        float m = x[a * 21];
#pragma unroll
        for (int c = 1; c < 21; c++) m = fmaxf(m, x[a * 21 + c]);
        float s = 0.f;
#pragma unroll
        for (int c = 0; c < 21; c++) { float e = expf(x[a * 21 + c] - m); x[a * 21 + c] = e; s += e; }
#pragma unroll
        for (int c = 0; c < 21; c++) {
            float sm = x[a * 21 + c] / s;           // mimic softmax: exp/sum
            int idx = a * 21 + c;
            if (sm > best) { best = sm; bi = idx; } // strict > = first-wins (jnp.argmax)
        }
    }
    cls_idx[t] = bi % 21;
}

// ---------------- K2: transpose source -> src, per-block per-class sums ----
__global__ __launch_bounds__(256) void k_trans_bs(const float* __restrict__ source,
                                                  const int* __restrict__ cls_idx,
                                                  float* __restrict__ src_out,
                                                  float* __restrict__ bs) {
    int b = blockIdx.x / NBn, m = blockIdx.x % NBn;
    int base = m * 64;
    int lane = threadIdx.x & 63, grp = threadIdx.x >> 6;
    __shared__ float tile[64][65];     // tile[c][j]
    __shared__ float bsw[4][21][64];
    __shared__ int cls[64];

    // coalesced load: tile[c][j] = source[b, c, base+j]
#pragma unroll
    for (int cc = 0; cc < 16; cc++) {
        int c = grp * 16 + cc;
        float v = 0.f;
        if (base + lane < Ln) v = source[((size_t)b * Cn + c) * Ln + base + lane];
        tile[c][lane] = v;
    }
    if (threadIdx.x < 64) {
        int k = 255;
        if (base + (int)threadIdx.x < Ln) k = cls_idx[b * Ln + base + threadIdx.x];
        cls[threadIdx.x] = k;
    }
    for (int i = threadIdx.x; i < 4 * 21 * 64; i += 256) ((float*)bsw)[i] = 0.f;
    __syncthreads();

    // write src (B,L,C) coalesced
#pragma unroll
    for (int jj = 0; jj < 16; jj++) {
        int j = grp * 16 + jj;
        if (base + j < Ln) src_out[((size_t)b * Ln + base + j) * Cn + lane] = tile[lane][j];
    }
    // partial per-class sums (each wave owns a j-range; lane = channel)
#pragma unroll
    for (int jj = 0; jj < 16; jj++) {
        int j = grp * 16 + jj;
        int k = cls[j];
        if (k < 21) bsw[grp][k][lane] += tile[lane][j];
    }
    __syncthreads();
    for (int i = threadIdx.x; i < 21 * 64; i += 256) {
        int k = i >> 6, c = i & 63;
        float v = bsw[0][k][c] + bsw[1][k][c] + bsw[2][k][c] + bsw[3][k][c];
        bs[(((size_t)b * NBn + m) * 21 + k) * 64 + c] = v;
    }
}

// ---------------- K3: exclusive block-prefix (in place) + totals + U -------
__global__ __launch_bounds__(256) void k_scan(const float* __restrict__ cls_r_prob,
                                              float* __restrict__ bs,   // in: BS, out: PS
                                              float* __restrict__ U) {
    int b = blockIdx.x;
    __shared__ float T[21 * 64];
    __shared__ float Rl[441];
    for (int i = threadIdx.x; i < 441; i += 256) Rl[i] = cls_r_prob[i];
    for (int p = threadIdx.x; p < 21 * 64; p += 256) {
        int k = p >> 6, c = p & 63;
        float run = 0.f;
        for (int m = 0; m < NBn; m++) {
            size_t idx = (((size_t)b * NBn + m) * 21 + k) * 64 + c;
            float v = bs[idx];
            bs[idx] = run;
            run += v;
        }
        T[p] = run;
    }
    __syncthreads();
    for (int p = threadIdx.x; p < 21 * 64; p += 256) {
        int a = p >> 6, c = p & 63;
        float u = 0.f;
        for (int k = 0; k < 21; k++) u += Rl[k * 21 + a] * T[k * 64 + c];
        U[((size_t)b * 21 + a) * 64 + c] = u;
    }
}

// ---------------- K4: final combine ----------------------------------------
__global__ __launch_bounds__(256) void k_final(const float* __restrict__ src,
                                               const int* __restrict__ cls_idx,
                                               const float* __restrict__ cls_r_prob,
                                               const float* __restrict__ ps,
                                               const float* __restrict__ U,
                                               float* __restrict__ fused) {
    int b = blockIdx.x / NBn, m = blockIdx.x % NBn;
    int base = m * 64;
    int lane = threadIdx.x & 63, grp = threadIdx.x >> 6;
    __shared__ float sT[64][64];      // sT[j][c]
    __shared__ float PSl[21][64];
    __shared__ float Ul[21][64];
    __shared__ float Rd[21][22];      // R[a,k]-R[k,a], padded
    __shared__ float Rdg[21];
    __shared__ int cls[64];

#pragma unroll
    for (int jj = 0; jj < 16; jj++) {
        int j = jj * 4 + grp;
        float v = 0.f;
        if (base + j < Ln) v = src[((size_t)b * Ln + base + j) * Cn + lane];
        sT[j][lane] = v;
    }
    for (int i = threadIdx.x; i < 21 * 64; i += 256) {
        PSl[i >> 6][i & 63] = ps[(((size_t)b * NBn + m) * 21) * 64 + i];
        Ul[i >> 6][i & 63] = U[((size_t)b * 21) * 64 + i];
    }
    for (int i = threadIdx.x; i < 441; i += 256) {
        int a = i / 21, k = i % 21;
        Rd[a][k] = cls_r_prob[a * 21 + k] - cls_r_prob[k * 21 + a];
    }
    if (threadIdx.x < 21) Rdg[threadIdx.x] = cls_r_prob[threadIdx.x * 21 + threadIdx.x];
    if (threadIdx.x < 64) {
        int k = 0;
        if (base + (int)threadIdx.x < Ln) k = cls_idx[b * Ln + base + threadIdx.x];
        cls[threadIdx.x] = k;
    }
    __syncthreads();

    for (int t = 0; t < 16; t++) {
        int i = grp + 4 * t;
        if (base + i >= Ln) break;
        int ci = cls[i];
        float acc = Ul[ci][lane] + (((ci != 0) ? 1.f : 0.f) - Rdg[ci]) * sT[i][lane];
#pragma unroll
        for (int k = 0; k < 21; k++) acc += Rd[ci][k] * PSl[k][lane];
        for (int j = 0; j < i; j++) acc += Rd[ci][cls[j]] * sT[j][lane];
        fused[((size_t)b * Ln + base + i) * Cn + lane] = acc;
    }
}

extern "C" void kernel_launch(void* const* d_in, const int* in_sizes, int n_in,
                              void* d_out, int out_size, void* d_ws, size_t ws_size,
                              hipStream_t stream) {
    const float* cls_pred = (const float*)d_in[0];
    const float* source = (const float*)d_in[1];
    const float* cls_r_prob = (const float*)d_in[2];
    // num_classes hardcoded (21)

    float* fused = (float*)d_out;
    float* src_out = fused + (size_t)Bn * Ln * Cn;

    char* w = (char*)d_ws;
    int* cls_idx = (int*)w;                                    // 16*1444*4 = 92416 B
    size_t off = ((size_t)Bn * Ln * 4 + 1023) & ~(size_t)1023; // -> 93184
    float* bs = (float*)(w + off);                             // 16*23*21*64*4 = 1978368 B
    float* U = bs + (size_t)Bn * NBn * 21 * 64;                // 16*21*64*4 = 86016 B

    hipLaunchKernelGGL(k_classify, dim3((Bn * Ln + 255) / 256), dim3(256), 0, stream,
                       cls_pred, cls_idx);
    hipLaunchKernelGGL(k_trans_bs, dim3(Bn * NBn), dim3(256), 0, stream,
                       source, cls_idx, src_out, bs);
    hipLaunchKernelGGL(k_scan, dim3(Bn), dim3(256), 0, stream,
                       cls_r_prob, bs, U);
    hipLaunchKernelGGL(k_final, dim3(Bn * NBn), dim3(256), 0, stream,
                       src_out, cls_idx, cls_r_prob, bs, U, fused);
}

// Round 2
// 71.755 us; speedup vs baseline: 1.0329x; 1.0329x over previous
//
#include <hip/hip_runtime.h>
#include <math.h>

#define Bn 16
#define Ln 1444      // 38*38
#define NCn 21
#define Cn 64
#define NBn 23       // ceil(1444/64)
#define KC 1344      // 21*64

// ---- Kernel A: classify + transpose + per-block per-class sums ------------
__global__ __launch_bounds__(256) void kA(const float* __restrict__ cls_pred,
                                          const float* __restrict__ source,
                                          int* __restrict__ cls_idx,
                                          float* __restrict__ src_out,
                                          float* __restrict__ bs) {
    int b = blockIdx.x / NBn, m = blockIdx.x % NBn;
    int base = m * 64;
    int lane = threadIdx.x & 63, grp = threadIdx.x >> 6;
    __shared__ float tile[64][65];     // tile[c][j]
    __shared__ float bsw[4][KC];       // per-wave per-class channel sums
    __shared__ int cls[64];

    // load tile[c][j] = source[b, c, base+j]  (coalesced)
#pragma unroll
    for (int cc = 0; cc < 16; cc++) {
        int c = grp * 16 + cc;
        float v = 0.f;
        if (base + lane < Ln) v = source[((size_t)b * Cn + c) * Ln + base + lane];
        tile[c][lane] = v;
    }

    // classify: thread = position p (64) x anchor a (4)
    {
        int p = threadIdx.x >> 2, a = threadIdx.x & 3;
        bool valid = (base + p < Ln);
        const float* q = cls_pred + ((size_t)b * Ln + base + p) * 84 + a * 21;
        float x[21];
#pragma unroll
        for (int i = 0; i < 21; i++) x[i] = valid ? q[i] : 0.f;
        float mx = x[0];
#pragma unroll
        for (int i = 1; i < 21; i++) mx = fmaxf(mx, x[i]);
        float s = 0.f;
#pragma unroll
        for (int i = 0; i < 21; i++) { x[i] = expf(x[i] - mx); s += x[i]; }
        float best = -1.f; int bi = 0;
#pragma unroll
        for (int i = 0; i < 21; i++) {
            float sm = x[i] / s;                     // mimic softmax exp/sum
            if (sm > best) { best = sm; bi = a * 21 + i; }  // first-wins within anchor
        }
        // reduce across the 4 anchor-lanes (consecutive lanes p*4..p*4+3)
#pragma unroll
        for (int d = 1; d <= 2; d <<= 1) {
            float ob = __shfl_xor(best, d);
            int oi = __shfl_xor(bi, d);
            if (ob > best || (ob == best && oi < bi)) { best = ob; bi = oi; }
        }
        if (a == 0) {
            if (valid) { int k = bi % 21; cls[p] = k; cls_idx[b * Ln + base + p] = k; }
            else cls[p] = 255;
        }
    }
    {
        float* f = &bsw[0][0];
        for (int i = threadIdx.x; i < 4 * KC; i += 256) f[i] = 0.f;
    }
    __syncthreads();

    // write src (B,L,C) coalesced
#pragma unroll
    for (int jj = 0; jj < 16; jj++) {
        int j = grp * 16 + jj;
        if (base + j < Ln) src_out[((size_t)b * Ln + base + j) * Cn + lane] = tile[lane][j];
    }
    // per-class partial sums (wave owns a j-range; lane = channel)
#pragma unroll
    for (int jj = 0; jj < 16; jj++) {
        int j = grp * 16 + jj;
        int k = cls[j];
        if (k < 21) bsw[grp][k * 64 + lane] += tile[lane][j];
    }
    __syncthreads();
    {
        const float* f = &bsw[0][0];
        for (int i = threadIdx.x; i < KC; i += 256) {
            float v = f[i] + f[KC + i] + f[2 * KC + i] + f[3 * KC + i];
            bs[((size_t)b * NBn + m) * KC + i] = v;
        }
    }
}

// ---- Kernel C: self-computed prefix + per-class running-sum combine -------
__global__ __launch_bounds__(256) void kC(const float* __restrict__ src,
                                          const int* __restrict__ cls_idx,
                                          const float* __restrict__ R,
                                          const float* __restrict__ bs,
                                          float* __restrict__ fused) {
    int b = blockIdx.x / NBn, m = blockIdx.x % NBn;
    int base = m * 64;
    int lane = threadIdx.x & 63, grp = threadIdx.x >> 6;
    __shared__ float sT[64][64];   // sT[j][c]
    __shared__ float PS[KC];       // [k*64+c] prefix over blocks < m
    __shared__ float Tt[KC];       // [k*64+c] batch totals
    __shared__ float Ul[KC];       // [a*64+c] = sum_k R[k][a]*T[k][c]
    __shared__ float MS[4][KC];    // per-wave running per-class sums
    __shared__ float Rd[21][22];   // R[a][k]-R[k][a]
    __shared__ float Rl[441];
    __shared__ float Rdg[21];
    __shared__ int cls[64];

    // load sT (coalesced from src written by kA)
#pragma unroll
    for (int jj = 0; jj < 16; jj++) {
        int j = grp * 16 + jj;
        float v = 0.f;
        if (base + j < Ln) v = src[((size_t)b * Ln + base + j) * Cn + lane];
        sT[j][lane] = v;
    }
    if (threadIdx.x < 64) {
        int k = 0;
        if (base + (int)threadIdx.x < Ln) k = cls_idx[b * Ln + base + threadIdx.x];
        cls[threadIdx.x] = k;
    }
    for (int i = threadIdx.x; i < 441; i += 256) {
        float r = R[i];
        Rl[i] = r;
        int aa = i / 21, kk = i % 21;
        Rd[aa][kk] = r - R[kk * 21 + aa];
    }
    if (threadIdx.x < 21) Rdg[threadIdx.x] = R[threadIdx.x * 22];   // diag
    // stream bs for the whole batch: prefix (<m) and totals
    for (int p0 = threadIdx.x; p0 < KC; p0 += 256) {
        float run = 0.f, psv = 0.f;
        for (int mm = 0; mm < NBn; mm++) {
            float v = bs[((size_t)b * NBn + mm) * KC + p0];
            if (mm < m) psv += v;
            run += v;
        }
        PS[p0] = psv; Tt[p0] = run;
    }
    __syncthreads();

    // Ul[a*64+c] = sum_k R[k][a] * T[k][c]
    for (int p0 = threadIdx.x; p0 < KC; p0 += 256) {
        int aa = p0 >> 6, c = p0 & 63;
        float u = 0.f;
#pragma unroll
        for (int k = 0; k < 21; k++) u += Rl[k * 21 + aa] * Tt[k * 64 + c];
        Ul[p0] = u;
    }
    {
        float* f = &MS[0][0];
        for (int i = threadIdx.x; i < 4 * KC; i += 256) f[i] = 0.f;
    }
    __syncthreads();

    // per-wave chunk class sums
#pragma unroll
    for (int jj = 0; jj < 16; jj++) {
        int j = grp * 16 + jj;
        int k = cls[j];
        MS[grp][k * 64 + lane] += sT[j][lane];
    }
    __syncthreads();

    // exclusive prefix over the 4 chunks, plus cross-block PS
    for (int p0 = threadIdx.x; p0 < KC; p0 += 256) {
        float c0 = MS[0][p0], c1 = MS[1][p0], c2 = MS[2][p0];
        float ps = PS[p0];
        MS[0][p0] = ps;
        MS[1][p0] = ps + c0;
        MS[2][p0] = ps + c0 + c1;
        MS[3][p0] = ps + c0 + c1 + c2;
    }
    __syncthreads();

    // serial over the wave's 16 positions, constant work per position
    int nvalid = (Ln - base < 64) ? (Ln - base) : 64;
    for (int t = 0; t < 16; t++) {
        int i = grp * 16 + t;
        if (i >= nvalid) break;
        int ci = cls[i];
        float acc = Ul[ci * 64 + lane] + (((ci != 0) ? 1.f : 0.f) - Rdg[ci]) * sT[i][lane];
#pragma unroll
        for (int k = 0; k < 21; k++) acc += Rd[ci][k] * MS[grp][k * 64 + lane];
        fused[((size_t)b * Ln + base + i) * Cn + lane] = acc;
        MS[grp][ci * 64 + lane] += sT[i][lane];   // include i for the next position
    }
}

extern "C" void kernel_launch(void* const* d_in, const int* in_sizes, int n_in,
                              void* d_out, int out_size, void* d_ws, size_t ws_size,
                              hipStream_t stream) {
    const float* cls_pred = (const float*)d_in[0];
    const float* source = (const float*)d_in[1];
    const float* cls_r_prob = (const float*)d_in[2];

    float* fused = (float*)d_out;
    float* src_out = fused + (size_t)Bn * Ln * Cn;

    char* w = (char*)d_ws;
    int* cls_idx = (int*)w;                                    // 92416 B
    size_t off = ((size_t)Bn * Ln * 4 + 1023) & ~(size_t)1023;
    float* bs = (float*)(w + off);                             // 16*23*1344*4 B

    hipLaunchKernelGGL(kA, dim3(Bn * NBn), dim3(256), 0, stream,
                       cls_pred, source, cls_idx, src_out, bs);
    hipLaunchKernelGGL(kC, dim3(Bn * NBn), dim3(256), 0, stream,
                       src_out, cls_idx, cls_r_prob, bs, fused);
}

// Round 3
// 40.804 us; speedup vs baseline: 1.8163x; 1.7586x over previous
//
#include <hip/hip_runtime.h>
#include <math.h>

#define Bn 16
#define Ln 1444      // 38*38
#define NCn 21
#define Cn 64
#define NBn 23       // ceil(1444/64)
#define KC 1344      // 21*64

// ---- Kernel B: classify + transpose + per-block per-class sums ------------
__global__ __launch_bounds__(256) void kB(const float* __restrict__ cls_pred,
                                          const float* __restrict__ source,
                                          int* __restrict__ cls_idx,
                                          float* __restrict__ src_out,
                                          float* __restrict__ bs) {
    int b = blockIdx.x / NBn, m = blockIdx.x % NBn;
    int base = m * 64;
    int lane = threadIdx.x & 63, grp = threadIdx.x >> 6;
    __shared__ float tile[64][65];     // tile[c][j]
    __shared__ float WS[4][KC];        // per-wave per-class channel sums
    __shared__ int cls[64];

    // load tile[c][j] = source[b, c, base+j]  (coalesced)
#pragma unroll
    for (int cc = 0; cc < 16; cc++) {
        int c = grp * 16 + cc;
        float v = 0.f;
        if (base + lane < Ln) v = source[((size_t)b * Cn + c) * Ln + base + lane];
        tile[c][lane] = v;
    }

    // classify: thread = position p (64) x anchor a (4)  (identical math to R2)
    {
        int p = threadIdx.x >> 2, a = threadIdx.x & 3;
        bool valid = (base + p < Ln);
        const float* q = cls_pred + ((size_t)b * Ln + base + p) * 84 + a * 21;
        float x[21];
#pragma unroll
        for (int i = 0; i < 21; i++) x[i] = valid ? q[i] : 0.f;
        float mx = x[0];
#pragma unroll
        for (int i = 1; i < 21; i++) mx = fmaxf(mx, x[i]);
        float s = 0.f;
#pragma unroll
        for (int i = 0; i < 21; i++) { x[i] = expf(x[i] - mx); s += x[i]; }
        float best = -1.f; int bi = 0;
#pragma unroll
        for (int i = 0; i < 21; i++) {
            float sm = x[i] / s;                     // mimic softmax exp/sum
            if (sm > best) { best = sm; bi = a * 21 + i; }
        }
#pragma unroll
        for (int d = 1; d <= 2; d <<= 1) {
            float ob = __shfl_xor(best, d);
            int oi = __shfl_xor(bi, d);
            if (ob > best || (ob == best && oi < bi)) { best = ob; bi = oi; }
        }
        if (a == 0) {
            if (valid) { int k = bi % 21; cls[p] = k; cls_idx[b * Ln + base + p] = k; }
            else cls[p] = 255;
        }
    }
    __syncthreads();

    // write src (B,L,C) coalesced
#pragma unroll
    for (int jj = 0; jj < 16; jj++) {
        int j = grp * 16 + jj;
        if (base + j < Ln) src_out[((size_t)b * Ln + base + j) * Cn + lane] = tile[lane][j];
    }

    // per-class sums of own 16 positions in REGISTERS (no LDS RMW chain)
    float cs[21];
#pragma unroll
    for (int k = 0; k < 21; k++) cs[k] = 0.f;
#pragma unroll
    for (int jj = 0; jj < 16; jj++) {
        int j = grp * 16 + jj;
        int k = cls[j];                      // wave-uniform broadcast
        float v = tile[lane][j];             // stride-65: conflict-free
#pragma unroll
        for (int kk = 0; kk < 21; kk++) cs[kk] += (kk == k) ? v : 0.f;
    }
#pragma unroll
    for (int kk = 0; kk < 21; kk++) WS[grp][kk * 64 + lane] = cs[kk];
    __syncthreads();

    for (int i = threadIdx.x; i < KC; i += 256) {
        float v = WS[0][i] + WS[1][i] + WS[2][i] + WS[3][i];
        bs[((size_t)b * NBn + m) * KC + i] = v;
    }
}

// ---- Kernel C: batched stream + register running sums ---------------------
__global__ __launch_bounds__(256) void kC(const float* __restrict__ src,
                                          const int* __restrict__ cls_idx,
                                          const float* __restrict__ R,
                                          const float* __restrict__ bs,
                                          float* __restrict__ fused) {
    int b = blockIdx.x / NBn, m = blockIdx.x % NBn;
    int base = m * 64;
    int lane = threadIdx.x & 63, grp = threadIdx.x >> 6;
    __shared__ float PS[KC];       // prefix over blocks < m
    __shared__ float Tt[KC];       // batch totals
    __shared__ float Ul[KC];       // [a*64+c] = sum_k R[k][a]*T[k][c]
    __shared__ float WS[4][KC];    // per-wave chunk class sums
    __shared__ float Rd[21][22];   // R[a][k]-R[k][a]
    __shared__ float Rl[441];
    __shared__ float Rdg[21];
    __shared__ int cls[64];

    // 1: own-chunk sT into 16 registers (issued first, consumed late)
    float sT[16];
#pragma unroll
    for (int t = 0; t < 16; t++) {
        int i = grp * 16 + t;
        sT[t] = (base + i < Ln) ? src[((size_t)b * Ln + base + i) * Cn + lane] : 0.f;
    }
    // 2: cls
    if (threadIdx.x < 64) {
        int k = 255;
        if (base + (int)threadIdx.x < Ln) k = cls_idx[b * Ln + base + threadIdx.x];
        cls[threadIdx.x] = k;
    }
    // 3: R tables
    for (int i = threadIdx.x; i < 441; i += 256) {
        float r = R[i];
        Rl[i] = r;
        int aa = i / 21, kk = i % 21;
        Rd[aa][kk] = r - R[kk * 21 + aa];
    }
    if (threadIdx.x < 21) Rdg[threadIdx.x] = R[threadIdx.x * 22];

    // 4: stream bs as float4 groups — 23 independent batched loads
    for (int g = threadIdx.x; g < KC / 4; g += 256) {
        float rx = 0.f, ry = 0.f, rz = 0.f, rw = 0.f;
        float px = 0.f, py = 0.f, pz = 0.f, pw = 0.f;
#pragma unroll
        for (int mm = 0; mm < NBn; mm++) {
            float4 v = *reinterpret_cast<const float4*>(&bs[((size_t)b * NBn + mm) * KC + g * 4]);
            rx += v.x; ry += v.y; rz += v.z; rw += v.w;
            if (mm < m) { px += v.x; py += v.y; pz += v.z; pw += v.w; }  // uniform branch
        }
        PS[g * 4] = px; PS[g * 4 + 1] = py; PS[g * 4 + 2] = pz; PS[g * 4 + 3] = pw;
        Tt[g * 4] = rx; Tt[g * 4 + 1] = ry; Tt[g * 4 + 2] = rz; Tt[g * 4 + 3] = rw;
    }
    __syncthreads();

    // 5: Ul[a*64+c] = sum_k R[k][a] * T[k][c]
    for (int p = threadIdx.x; p < KC; p += 256) {
        int aa = p >> 6, c = p & 63;
        float u = 0.f;
#pragma unroll
        for (int k = 0; k < 21; k++) u += Rl[k * 21 + aa] * Tt[k * 64 + c];
        Ul[p] = u;
    }

    // 6: own-chunk per-class sums in registers -> WS
    float cs[21];
#pragma unroll
    for (int k = 0; k < 21; k++) cs[k] = 0.f;
#pragma unroll
    for (int t = 0; t < 16; t++) {
        int j = grp * 16 + t;
        int k = cls[j];
        float v = sT[t];
#pragma unroll
        for (int kk = 0; kk < 21; kk++) cs[kk] += (kk == k) ? v : 0.f;
    }
#pragma unroll
    for (int kk = 0; kk < 21; kk++) WS[grp][kk * 64 + lane] = cs[kk];
    __syncthreads();

    // 7: register running sums: ms[k] = PS + chunks before mine
    float ms[21];
#pragma unroll
    for (int k = 0; k < 21; k++) {
        float x = PS[k * 64 + lane];
#pragma unroll
        for (int g = 0; g < 3; g++)
            if (g < grp) x += WS[g][k * 64 + lane];
        ms[k] = x;
    }

    // 8: serial over own 16 positions — register-only dependency chain
    int nvalid = (Ln - base < 64) ? (Ln - base) : 64;
    for (int t = 0; t < 16; t++) {
        int i = grp * 16 + t;
        if (i >= nvalid) break;
        int ci = cls[i];                                 // wave-uniform
        float acc = Ul[ci * 64 + lane] + (((ci != 0) ? 1.f : 0.f) - Rdg[ci]) * sT[t];
#pragma unroll
        for (int k = 0; k < 21; k++) acc += Rd[ci][k] * ms[k];   // broadcast read + reg FMA
        fused[((size_t)b * Ln + base + i) * Cn + lane] = acc;
        float v = sT[t];
#pragma unroll
        for (int kk = 0; kk < 21; kk++) ms[kk] += (kk == ci) ? v : 0.f;
    }
}

extern "C" void kernel_launch(void* const* d_in, const int* in_sizes, int n_in,
                              void* d_out, int out_size, void* d_ws, size_t ws_size,
                              hipStream_t stream) {
    const float* cls_pred = (const float*)d_in[0];
    const float* source = (const float*)d_in[1];
    const float* cls_r_prob = (const float*)d_in[2];

    float* fused = (float*)d_out;
    float* src_out = fused + (size_t)Bn * Ln * Cn;

    char* w = (char*)d_ws;
    int* cls_idx = (int*)w;                                    // 92416 B
    size_t off = ((size_t)Bn * Ln * 4 + 1023) & ~(size_t)1023;
    float* bs = (float*)(w + off);                             // 16*23*1344*4 B

    hipLaunchKernelGGL(kB, dim3(Bn * NBn), dim3(256), 0, stream,
                       cls_pred, source, cls_idx, src_out, bs);
    hipLaunchKernelGGL(kC, dim3(Bn * NBn), dim3(256), 0, stream,
                       src_out, cls_idx, cls_r_prob, bs, fused);
}